// Round 13
// baseline (266.309 us; speedup 1.0000x reference)
//
#include <hip/hip_runtime.h>
#include <math.h>

// Problem constants (from reference)
#define Bb 2
#define Ll 2048
#define Dd 512
#define Hh 8
#define DKq 64
#define NBUCK 16
#define KMAX 64
#define MAX_ITEMS 1280   // exact bound: 16 bh * (64 + 16) chunks of 32

// ---------------------------------------------------------------------------
// Direct global->LDS DMA (gfx950), 16B per lane.  LDS dest = uniform base +
// lane*16 (linear); per-lane GLOBAL address carries any swizzle (m173/m201).
// ---------------------------------------------------------------------------
__device__ __forceinline__ void gl_lds16(const float* g, float* l) {
  __builtin_amdgcn_global_load_lds(
      (const __attribute__((address_space(1))) void*)g,
      (__attribute__((address_space(3))) void*)l, 16, 0, 0);
}

// Counted vmcnt wait, NO barrier (single-wave blocks are self-paced).
// vmcnt retires IN ORDER (round-11 lesson): with only staging DMAs on the
// counter, vmcnt(6) == "tile t's 6 loads done, t+1's 6 may fly".
#define VM_WAIT(N)                                                \
  do {                                                            \
    asm volatile("s_waitcnt vmcnt(" #N ")" ::: "memory");         \
    __builtin_amdgcn_sched_barrier(0);                            \
  } while (0)

// ---------------------------------------------------------------------------
// Projection GEMM: X(4096x512) @ W(512x512) + b -> (b,h,l,dk) scatter.
// Round-13: single-wave blocks, BM=32 BN=64 BK=16, 8x4 microtile,
// grid (8,128,3) = 3072 blocks = 12 waves/CU = 3 waves/SIMD.
// Round-12 analysis: all prior schedules ran 6 waves/CU (1.5/SIMD) and were
// DEPENDENT-LOAD LATENCY bound (VALUBusy pinned ~45%); LDS distinct-byte
// traffic is tiny (broadcast reads are free), so more TLP is the lever.
// LDS 12 KB/block x 12 = 144 KB/CU.  DMA staging + counted vmcnt(6), no
// barrier.  A staged with k4 XOR (row>>3) swizzle via pre-swizzled DMA
// source -> A-reads hit 4 distinct bank-quads (conflict-free); B-reads
// 2-way (free).  Per-output FMA chain is ascending-k, one fma per k ->
// bit-identical q/k vs all prior rounds (LSH sign-critical).
// ---------------------------------------------------------------------------
__global__ __launch_bounds__(64) void proj_kernel(
    const float* __restrict__ Xq, const float* __restrict__ Xk, const float* __restrict__ Xv,
    const float* __restrict__ Wq, const float* __restrict__ Wk, const float* __restrict__ Wv,
    const float* __restrict__ bq, const float* __restrict__ bk, const float* __restrict__ bv,
    float* __restrict__ qb, float* __restrict__ kb, float* __restrict__ vb)
{
  const float *X, *W, *bias; float* dst;
  if (blockIdx.z == 0)      { X=Xq; W=Wq; bias=bq; dst=qb; }
  else if (blockIdx.z == 1) { X=Xk; W=Wk; bias=bk; dst=kb; }
  else                      { X=Xv; W=Wv; bias=bv; dst=vb; }
  __shared__ float As[2][32 * 16];    // [buf][m][k4 swizzled]  2 KB each
  __shared__ float Bs[2][16 * 64];    // [buf][k][n]            4 KB each
  const int lane = threadIdx.x;                 // one wave
  const int m0 = blockIdx.y * 32;
  const int n0 = blockIdx.x * 64;
  const int tx = lane & 15, ty = lane >> 4;     // 16 x 4 grid; 8x4 microtile

  // A DMA source, pre-swizzled: LDS slot s of row m holds X[m][(s^((m>>3)&3))*4..].
  const float* aSrc[2];
  #pragma unroll
  for (int j = 0; j < 2; j++) {
    int row  = 16*j + (lane >> 2);              // 0..31
    int key  = (row >> 3) & 3;
    int sK4  = (lane & 3) ^ key;
    aSrc[j] = X + (size_t)(m0 + row) * 512 + (sK4 << 2);
  }
  // B DMA source (linear): instr j covers k-rows 4j..4j+3 of the 16x64 tile.
  const float* bSrc[4];
  #pragma unroll
  for (int j = 0; j < 4; j++) {
    int krow = 4*j + (lane >> 4);               // 0..15
    bSrc[j] = W + (size_t)krow * 512 + n0 + ((lane & 15) << 2);
  }

  // Prologue: stage tile 0 into buf 0 (6 loads).
  #pragma unroll
  for (int j = 0; j < 2; j++) gl_lds16(aSrc[j], &As[0][j*256]);
  #pragma unroll
  for (int j = 0; j < 4; j++) gl_lds16(bSrc[j], &Bs[0][j*256]);

  float acc[8][4] = {};
  for (int t = 0; t < 32; t++) {
    const int cur = t & 1;
    if (t < 31) {                               // stage tile t+1 (6 loads)
      const int ks = (t + 1) * 16;
      const int nb = cur ^ 1;
      #pragma unroll
      for (int j = 0; j < 2; j++) gl_lds16(aSrc[j] + ks,              &As[nb][j*256]);
      #pragma unroll
      for (int j = 0; j < 4; j++) gl_lds16(bSrc[j] + (size_t)ks*512,  &Bs[nb][j*256]);
      VM_WAIT(6);                               // tile t landed; t+1 in flight
    } else {
      VM_WAIT(0);
    }

    const float* Ac = &As[cur][0];
    const float* Bc = &Bs[cur][0];
    #pragma unroll
    for (int kk4 = 0; kk4 < 4; kk4++) {
      float4 a[8];
      #pragma unroll
      for (int i = 0; i < 8; i++)
        a[i] = *(const float4*)&Ac[(ty*8 + i)*16 + ((kk4 ^ ty) << 2)];
      #pragma unroll
      for (int s = 0; s < 4; s++) {
        const int kk = kk4*4 + s;
        float4 b0 = *(const float4*)&Bc[kk*64 + tx*4];
        #pragma unroll
        for (int i = 0; i < 8; i++) {
          const float as = (s==0) ? a[i].x : (s==1) ? a[i].y
                         : (s==2) ? a[i].z : a[i].w;
          acc[i][0] += as * b0.x;  acc[i][1] += as * b0.y;
          acc[i][2] += as * b0.z;  acc[i][3] += as * b0.w;
        }
      }
    }
    // 2-buffer safety (single wave): buf[cur^1] is only overwritten by the
    // NEXT iteration's stage, issued after these ds_reads in program order.
  }

  const int head = n0 >> 6;            // BN=64 == one head
  const int d0 = tx * 4;
  #pragma unroll
  for (int i = 0; i < 8; i++) {
    int m = m0 + ty*8 + i;
    int b = m >> 11, l = m & 2047;
    float* drow = &dst[(((size_t)b*Hh + head)*Ll + l)*DKq];
    #pragma unroll
    for (int j = 0; j < 4; j++) drow[d0 + j] = acc[i][j] + bias[n0 + tx*4 + j];
  }
}

// ---------------------------------------------------------------------------
// LSH hash (unchanged)
// ---------------------------------------------------------------------------
__global__ __launch_bounds__(256) void hash_kernel(
    const float* __restrict__ qb, const float* __restrict__ kb,
    const float* __restrict__ rv, int* __restrict__ qhash, int* __restrict__ khash)
{
  int gwave = (blockIdx.x * blockDim.x + threadIdx.x) >> 6;
  int lane = threadIdx.x & 63;
  const int NR = Bb * Hh * Ll;
  if (gwave >= 2 * NR) return;
  int isK = gwave >= NR;
  int row = isK ? gwave - NR : gwave;
  int h = (row >> 11) & 7;
  const float* src = isK ? kb : qb;
  float x = src[(size_t)row * DKq + lane];
  float r = rv[h * DKq + lane];
  float v = (x > 0.0f) ? r : 0.0f;
  #pragma unroll
  for (int off = 32; off; off >>= 1) v += __shfl_xor(v, off);
  if (lane == 0) {
    float fb = floorf(v * 0.125f);
    int ib = (int)fb;
    int bucket = ib & 15;
    (isK ? khash : qhash)[row] = bucket;
  }
}

// ---------------------------------------------------------------------------
// First <=64 ascending key indices per (b,h,bucket) (unchanged)
// ---------------------------------------------------------------------------
__global__ __launch_bounds__(64) void kcand_kernel(
    const int* __restrict__ khash, int* __restrict__ kcand, int* __restrict__ kcount)
{
  int bh = blockIdx.x >> 4;
  int bucket = blockIdx.x & 15;
  int lane = threadIdx.x;
  const int* kh = &khash[bh * Ll];
  int* cl = &kcand[(size_t)blockIdx.x * KMAX];
  int total = 0;
  for (int c0 = 0; c0 < Ll && total < KMAX; c0 += 64) {
    int hv = kh[c0 + lane];
    unsigned long long m = __ballot(hv == bucket);
    int pre = __popcll(m & ((1ULL << lane) - 1ULL));
    if (hv == bucket && total + pre < KMAX) cl[total + pre] = c0 + lane;
    total += __popcll(m);
  }
  if (lane == 0) kcount[blockIdx.x] = total < KMAX ? total : KMAX;
}

// ---------------------------------------------------------------------------
// Group queries by bucket per (b,h) (unchanged)
// ---------------------------------------------------------------------------
__global__ __launch_bounds__(256) void qlist_kernel(
    const int* __restrict__ qhash, int* __restrict__ qoff, int* __restrict__ qlist)
{
  int bh = blockIdx.x;
  __shared__ int cnt[NBUCK], cur[NBUCK], off[NBUCK + 1];
  if (threadIdx.x < NBUCK) cnt[threadIdx.x] = 0;
  __syncthreads();
  const int* qh = &qhash[bh * Ll];
  for (int l = threadIdx.x; l < Ll; l += 256) atomicAdd(&cnt[qh[l]], 1);
  __syncthreads();
  if (threadIdx.x == 0) {
    int s = 0;
    for (int i = 0; i < NBUCK; i++) { off[i] = s; cur[i] = s; s += cnt[i]; }
    off[NBUCK] = s;
  }
  __syncthreads();
  if (threadIdx.x < NBUCK + 1) qoff[bh * (NBUCK + 1) + threadIdx.x] = off[threadIdx.x];
  for (int l = threadIdx.x; l < Ll; l += 256) {
    int p = atomicAdd(&cur[qh[l]], 1);
    qlist[bh * Ll + p] = l;
  }
}

// ---------------------------------------------------------------------------
// Deterministic worklist: one item per active (bh,bucket,chunk-of-32-queries).
// ---------------------------------------------------------------------------
__global__ __launch_bounds__(256) void worklist_kernel(
    const int* __restrict__ qoff, const int* __restrict__ kcount,
    int4* __restrict__ items, int* __restrict__ nitems)
{
  int t = threadIdx.x;
  int bh = t >> 4, bucket = t & 15;
  int o0 = qoff[bh * 17 + bucket], o1 = qoff[bh * 17 + bucket + 1];
  int cnt = kcount[t];
  int nq = o1 - o0;
  int n = (cnt > 0) ? ((nq + 31) >> 5) : 0;
  __shared__ int sc[256];
  sc[t] = n;
  __syncthreads();
  for (int off = 1; off < 256; off <<= 1) {
    int v = (t >= off) ? sc[t - off] : 0;
    __syncthreads();
    sc[t] += v;
    __syncthreads();
  }
  int start = sc[t] - n;
  for (int i = 0; i < n; i++) {
    int q0 = 32 * i;
    int qn = nq - q0; if (qn > 32) qn = 32;
    items[start + i] = make_int4(t, o0 + q0, qn, cnt);
  }
  if (t == 255) nitems[0] = sc[255];
}

// ---------------------------------------------------------------------------
// LDS fence for same-wave cross-lane LDS dependences (rule #18).
// ---------------------------------------------------------------------------
__device__ __forceinline__ void lds_fence() {
  asm volatile("s_waitcnt lgkmcnt(0)" ::: "memory");
  __builtin_amdgcn_sched_barrier(0);
}

// ---------------------------------------------------------------------------
// Attention: one WAVE per item (<=32 q x <=64 cand x 64 dim).  K rows in
// regs (lane=c), V^T in regs (lane=d), Q via wave-private LDS broadcasts.
// (unchanged -- correctness-verified rounds 4/6/7/8/9/10/11/12)
// ---------------------------------------------------------------------------
__global__ __launch_bounds__(256, 2) void attn_kernel(
    const float* __restrict__ qb, const float* __restrict__ kb, const float* __restrict__ vb,
    const int* __restrict__ qlist, const int* __restrict__ kcand,
    const int4* __restrict__ items, const int* __restrict__ nitems,
    float* __restrict__ ctx)
{
  __shared__ float qs_all[4][32 * 64];
  __shared__ float sa_all[4][64];
  const int wid = threadIdx.x >> 6, lane = threadIdx.x & 63;
  const int idx = blockIdx.x * 4 + wid;
  if (idx >= nitems[0]) return;          // wave-uniform exit
  const int4 it = items[idx];
  const int code = it.x, qstart = it.y, qn = it.z, cnt = it.w;
  const int bh = code >> 4;
  float* qs = qs_all[wid];
  float* sa = sa_all[wid];

  const float* qbh = qb + (size_t)bh * Ll * DKq;
  const float* kbh = kb + (size_t)bh * Ll * DKq;
  const float* vbh = vb + (size_t)bh * Ll * DKq;

  int qidx_v = (lane < qn)  ? qlist[bh * Ll + qstart + lane] : 0;
  int cidx_v = (lane < cnt) ? kcand[(size_t)code * KMAX + lane] : 0;

  float4 kr[16];
  {
    const float4* krow = (const float4*)kbh + (size_t)cidx_v * 16;
    #pragma unroll
    for (int i = 0; i < 16; i++) kr[i] = krow[i];
  }
  float vt[64];
  #pragma unroll
  for (int c = 0; c < 64; c++) {
    int rowc = __shfl(cidx_v, c);
    vt[c] = vbh[(size_t)rowc * DKq + lane];
  }
  #pragma unroll
  for (int i = 0; i < 8; i++) {
    int f = lane + 64 * i;
    int r = f >> 4, c4 = f & 15;
    int qrow = __shfl(qidx_v, r);
    float4 qv = *((const float4*)qbh + (size_t)qrow * 16 + c4);
    *(float4*)&qs[r * 64 + c4 * 4] = qv;
  }
  lds_fence();

  const int b = bh >> 3, h = bh & 7;
  const float4* qs4 = (const float4*)qs;
  const float4* sa4 = (const float4*)sa;

  for (int j = 0; j < qn; j++) {
    float s0 = 0.f, s1 = 0.f, s2 = 0.f, s3 = 0.f;
    #pragma unroll
    for (int i = 0; i < 16; i += 4) {
      float4 q0 = qs4[j * 16 + i + 0];
      float4 q1 = qs4[j * 16 + i + 1];
      float4 q2 = qs4[j * 16 + i + 2];
      float4 q3 = qs4[j * 16 + i + 3];
      s0 += q0.x*kr[i+0].x + q0.y*kr[i+0].y + q0.z*kr[i+0].z + q0.w*kr[i+0].w;
      s1 += q1.x*kr[i+1].x + q1.y*kr[i+1].y + q1.z*kr[i+1].z + q1.w*kr[i+1].w;
      s2 += q2.x*kr[i+2].x + q2.y*kr[i+2].y + q2.z*kr[i+2].z + q2.w*kr[i+2].w;
      s3 += q3.x*kr[i+3].x + q3.y*kr[i+3].y + q3.z*kr[i+3].z + q3.w*kr[i+3].w;
    }
    float s = ((s0 + s1) + (s2 + s3)) * 0.125f;
    s = (lane < cnt) ? s : -INFINITY;
    float m = s;
    #pragma unroll
    for (int off = 32; off; off >>= 1) m = fmaxf(m, __shfl_xor(m, off));
    float e = __expf(s - m);
    float sum = e;
    #pragma unroll
    for (int off = 32; off; off >>= 1) sum += __shfl_xor(sum, off);
    lds_fence();
    sa[lane] = e;
    lds_fence();
    float c0 = 0.f, c1 = 0.f, c2 = 0.f, c3 = 0.f;
    #pragma unroll
    for (int i = 0; i < 16; i++) {
      float4 a = sa4[i];
      c0 += a.x * vt[4*i + 0];
      c1 += a.y * vt[4*i + 1];
      c2 += a.z * vt[4*i + 2];
      c3 += a.w * vt[4*i + 3];
    }
    float ctxd = ((c0 + c1) + (c2 + c3)) / sum;
    int qrow = __shfl(qidx_v, j);
    ctx[((size_t)(b * Ll + qrow)) * 512 + h * 64 + lane] = ctxd;
  }
}

// ---------------------------------------------------------------------------
// T[h,dk,n] = sum_r U[h,dk,r] * V[h,r,n]  (unchanged)
// ---------------------------------------------------------------------------
__global__ __launch_bounds__(256) void uv_kernel(
    const float* __restrict__ U, const float* __restrict__ V, float* __restrict__ T)
{
  int idx = blockIdx.x * 256 + threadIdx.x;
  int n = idx & 511, dk = (idx >> 9) & 63, h = idx >> 15;
  float acc = 0.f;
  #pragma unroll
  for (int r = 0; r < 32; r++)
    acc += U[((size_t)h * 64 + dk) * 32 + r] * V[((size_t)h * 32 + r) * 512 + n];
  T[idx] = acc;
}

// ---------------------------------------------------------------------------
// Mf[h*64+dk, n] = sum_c T[h,dk,c] * Wo[h*512+c, n].  (unchanged)
// ---------------------------------------------------------------------------
__global__ __launch_bounds__(256) void m_kernel(
    const float* __restrict__ T, const float* __restrict__ Wo, float* __restrict__ Mf)
{
  __shared__ float Ts[16][68];
  __shared__ float Ws[16][68];
  const int h = blockIdx.y;
  const int n0 = blockIdx.x * 64;
  const int tid = threadIdx.x;
  const int tx = tid & 15, ty = tid >> 4;
  float acc[4][4] = {};
  for (int k0 = 0; k0 < 512; k0 += 16) {
    {
      int r = tid >> 2, cg = (tid & 3) << 2;
      float4 a = *(const float4*)&T[((size_t)(h*64 + r))*512 + k0 + cg];
      Ts[cg+0][r]=a.x; Ts[cg+1][r]=a.y; Ts[cg+2][r]=a.z; Ts[cg+3][r]=a.w;
    }
    {
      int row = tid >> 4, c4 = tid & 15;
      *(float4*)&Ws[row][c4*4] = *(const float4*)&Wo[((size_t)(h*512 + k0 + row))*512 + n0 + c4*4];
    }
    __syncthreads();
    #pragma unroll
    for (int kk = 0; kk < 16; kk++) {
      float4 a0 = *(const float4*)&Ts[kk][ty*4];
      float4 b0 = *(const float4*)&Ws[kk][tx*4];
      float av[4] = {a0.x,a0.y,a0.z,a0.w};
      float bw[4] = {b0.x,b0.y,b0.z,b0.w};
      #pragma unroll
      for (int i=0;i<4;i++)
        #pragma unroll
        for (int j=0;j<4;j++) acc[i][j] += av[i]*bw[j];
    }
    __syncthreads();
  }
  #pragma unroll
  for (int i=0;i<4;i++) {
    int row = h*64 + ty*4 + i;
    #pragma unroll
    for (int j=0;j<4;j++)
      Mf[(size_t)row * 512 + n0 + tx*4 + j] = acc[i][j];
  }
}

// ---------------------------------------------------------------------------
// OUT(4096x512) = CTX @ Mf + bo.  (unchanged from rounds 7-12)
// ---------------------------------------------------------------------------
__global__ __launch_bounds__(128) void out_gemm(
    const float* __restrict__ A, const float* __restrict__ Bm,
    const float* __restrict__ bias, float* __restrict__ C)
{
  __shared__ float As[32][68];
  __shared__ float Bs[32][68];
  const int tid = threadIdx.x;
  const int m0 = blockIdx.y * 64, n0 = blockIdx.x * 64;
  const int tx = tid & 15, ty = tid >> 4;

  float4 ar[4], br[4];
  #pragma unroll
  for (int i = 0; i < 4; i++) {
    int g = i * 128 + tid, row = g >> 3, c4 = g & 7;
    ar[i] = *(const float4*)&A[(size_t)(m0 + row) * 512 + c4 * 4];
  }
  #pragma unroll
  for (int i = 0; i < 4; i++) {
    int g = i * 128 + tid, row = g >> 4, c4 = g & 15;
    br[i] = *(const float4*)&Bm[(size_t)row * 512 + n0 + c4 * 4];
  }

  float acc[8][4] = {};
  for (int k0 = 0; k0 < 512; k0 += 32) {
    __syncthreads();
    #pragma unroll
    for (int i = 0; i < 4; i++) {
      int g = i * 128 + tid, row = g >> 3, c4 = g & 7;
      int mswz = ((c4 >> 1) & 1) << 3;
      As[c4*4+0][(row ^ mswz)] = ar[i].x;
      As[c4*4+1][(row ^ mswz)] = ar[i].y;
      As[c4*4+2][(row ^ mswz)] = ar[i].z;
      As[c4*4+3][(row ^ mswz)] = ar[i].w;
    }
    #pragma unroll
    for (int i = 0; i < 4; i++) {
      int g = i * 128 + tid, row = g >> 4, c4 = g & 15;
      *(float4*)&Bs[row][c4*4] = br[i];
    }
    __syncthreads();
    if (k0 + 32 < 512) {
      #pragma unroll
      for (int i = 0; i < 4; i++) {
        int g = i * 128 + tid, row = g >> 3, c4 = g & 7;
        ar[i] = *(const float4*)&A[(size_t)(m0 + row) * 512 + (k0 + 32) + c4 * 4];
      }
      #pragma unroll
      for (int i = 0; i < 4; i++) {
        int g = i * 128 + tid, row = g >> 4, c4 = g & 15;
        br[i] = *(const float4*)&Bm[(size_t)(k0 + 32 + row) * 512 + n0 + c4 * 4];
      }
    }
    #pragma unroll
    for (int kk = 0; kk < 32; kk++) {
      const int mswz = ((kk >> 3) & 1) << 3;
      const int mb = (ty * 8) ^ mswz;
      float4 a0 = *(const float4*)&As[kk][mb];
      float4 a1 = *(const float4*)&As[kk][mb + 4];
      float4 b0 = *(const float4*)&Bs[kk][tx*4];
      float av[8] = {a0.x,a0.y,a0.z,a0.w,a1.x,a1.y,a1.z,a1.w};
      float bw[4] = {b0.x,b0.y,b0.z,b0.w};
      #pragma unroll
      for (int i=0;i<8;i++)
        #pragma unroll
        for (int j=0;j<4;j++) acc[i][j] += av[i]*bw[j];
    }
  }
  #pragma unroll
  for (int i=0;i<8;i++) {
    int m = m0 + ty*8 + i;
    #pragma unroll
    for (int j=0;j<4;j++) {
      int n = n0 + tx*4 + j;
      C[(size_t)m * 512 + n] = acc[i][j] + bias[n];
    }
  }
}

// ---------------------------------------------------------------------------
extern "C" void kernel_launch(void* const* d_in, const int* in_sizes, int n_in,
                              void* d_out, int out_size, void* d_ws, size_t ws_size,
                              hipStream_t stream)
{
  const float* query = (const float*)d_in[0];
  const float* key   = (const float*)d_in[1];
  const float* value = (const float*)d_in[2];
  const float* Wq = (const float*)d_in[3];
  const float* bq = (const float*)d_in[4];
  const float* Wk = (const float*)d_in[5];
  const float* bk = (const float*)d_in[6];
  const float* Wv = (const float*)d_in[7];
  const float* bv = (const float*)d_in[8];
  const float* U  = (const float*)d_in[9];
  const float* V  = (const float*)d_in[10];
  const float* rv = (const float*)d_in[11];
  const float* Wo = (const float*)d_in[12];
  const float* bo = (const float*)d_in[13];
  float* out = (float*)d_out;

  float* ws = (float*)d_ws;
  const size_t NQKV = (size_t)Bb * Hh * Ll * DKq;
  float* qb   = ws;
  float* kb   = qb + NQKV;
  float* vb   = kb + NQKV;
  float* ctx  = vb + NQKV;
  float* T    = ctx + NQKV;
  float* Mf   = T + (size_t)Hh * DKq * 512;
  int* qhash  = (int*)(Mf + 512 * 512);
  int* khash  = qhash + Bb * Hh * Ll;
  int* kcand  = khash + Bb * Hh * Ll;
  int* kcount = kcand + Bb * Hh * NBUCK * KMAX;
  int* qoff   = kcount + Bb * Hh * NBUCK;
  int* qlist  = qoff + Bb * Hh * (NBUCK + 1);
  int4* items = (int4*)(qlist + Bb * Hh * Ll);    // 16B-aligned offset
  int* nitems = (int*)(items + MAX_ITEMS);

  proj_kernel<<<dim3(8, 128, 3), 64, 0, stream>>>(query, key, value,
                                                  Wq, Wk, Wv, bq, bk, bv,
                                                  qb, kb, vb);
  hash_kernel<<<(2 * Bb * Hh * Ll * 64) / 256, 256, 0, stream>>>(qb, kb, rv, qhash, khash);
  kcand_kernel<<<Bb * Hh * NBUCK, 64, 0, stream>>>(khash, kcand, kcount);
  qlist_kernel<<<Bb * Hh, 256, 0, stream>>>(qhash, qoff, qlist);
  worklist_kernel<<<1, 256, 0, stream>>>(qoff, kcount, items, nitems);
  attn_kernel<<<MAX_ITEMS / 4, 256, 0, stream>>>(qb, kb, vb, qlist, kcand,
                                                 items, nitems, ctx);
  uv_kernel<<<(Hh * DKq * 512) / 256, 256, 0, stream>>>(U, V, T);
  m_kernel<<<dim3(8, 8), 256, 0, stream>>>(T, Wo, Mf);
  out_gemm<<<dim3(8, 64), 128, 0, stream>>>(ctx, Mf, bo, out);
}

// Round 15
// 259.375 us; speedup vs baseline: 1.0267x; 1.0267x over previous
//
#include <hip/hip_runtime.h>
#include <math.h>

// Problem constants (from reference)
#define Bb 2
#define Ll 2048
#define Dd 512
#define Hh 8
#define DKq 64
#define NBUCK 16
#define KMAX 64
#define MAX_ITEMS 1280   // exact bound: 16 bh * (64 + 16) chunks of 32

// ---------------------------------------------------------------------------
// Direct global->LDS DMA (gfx950), 16B per lane.  LDS dest = uniform base +
// lane*16 (linear); per-lane GLOBAL address carries any swizzle (m173/m201).
// ---------------------------------------------------------------------------
__device__ __forceinline__ void gl_lds16(const float* g, float* l) {
  __builtin_amdgcn_global_load_lds(
      (const __attribute__((address_space(1))) void*)g,
      (__attribute__((address_space(3))) void*)l, 16, 0, 0);
}

// Counted vmcnt wait, NO barrier (single-wave blocks are self-paced).
// vmcnt retires IN ORDER (round-11 lesson): with only staging DMAs on the
// counter, vmcnt(6) == "tile t's 6 loads done, t+1's 6 may fly".
#define VM_WAIT(N)                                                \
  do {                                                            \
    asm volatile("s_waitcnt vmcnt(" #N ")" ::: "memory");         \
    __builtin_amdgcn_sched_barrier(0);                            \
  } while (0)

// ---------------------------------------------------------------------------
// Projection GEMM (UNCHANGED from round 13 -- 92 us, VALUBusy 60%).
// Single-wave blocks, BM=32 BN=64 BK=16, 8x4 microtile, grid (8,128,3) =
// 3072 blocks = 12 waves/CU.  DMA staging + counted vmcnt(6), no barrier.
// Per-output FMA chain is ascending-k -> bit-identical q/k (LSH-critical).
// ---------------------------------------------------------------------------
__global__ __launch_bounds__(64) void proj_kernel(
    const float* __restrict__ Xq, const float* __restrict__ Xk, const float* __restrict__ Xv,
    const float* __restrict__ Wq, const float* __restrict__ Wk, const float* __restrict__ Wv,
    const float* __restrict__ bq, const float* __restrict__ bk, const float* __restrict__ bv,
    float* __restrict__ qb, float* __restrict__ kb, float* __restrict__ vb)
{
  const float *X, *W, *bias; float* dst;
  if (blockIdx.z == 0)      { X=Xq; W=Wq; bias=bq; dst=qb; }
  else if (blockIdx.z == 1) { X=Xk; W=Wk; bias=bk; dst=kb; }
  else                      { X=Xv; W=Wv; bias=bv; dst=vb; }
  __shared__ float As[2][32 * 16];
  __shared__ float Bs[2][16 * 64];
  const int lane = threadIdx.x;
  const int m0 = blockIdx.y * 32;
  const int n0 = blockIdx.x * 64;
  const int tx = lane & 15, ty = lane >> 4;

  const float* aSrc[2];
  #pragma unroll
  for (int j = 0; j < 2; j++) {
    int row  = 16*j + (lane >> 2);
    int key  = (row >> 3) & 3;
    int sK4  = (lane & 3) ^ key;
    aSrc[j] = X + (size_t)(m0 + row) * 512 + (sK4 << 2);
  }
  const float* bSrc[4];
  #pragma unroll
  for (int j = 0; j < 4; j++) {
    int krow = 4*j + (lane >> 4);
    bSrc[j] = W + (size_t)krow * 512 + n0 + ((lane & 15) << 2);
  }

  #pragma unroll
  for (int j = 0; j < 2; j++) gl_lds16(aSrc[j], &As[0][j*256]);
  #pragma unroll
  for (int j = 0; j < 4; j++) gl_lds16(bSrc[j], &Bs[0][j*256]);

  float acc[8][4] = {};
  for (int t = 0; t < 32; t++) {
    const int cur = t & 1;
    if (t < 31) {
      const int ks = (t + 1) * 16;
      const int nb = cur ^ 1;
      #pragma unroll
      for (int j = 0; j < 2; j++) gl_lds16(aSrc[j] + ks,              &As[nb][j*256]);
      #pragma unroll
      for (int j = 0; j < 4; j++) gl_lds16(bSrc[j] + (size_t)ks*512,  &Bs[nb][j*256]);
      VM_WAIT(6);
    } else {
      VM_WAIT(0);
    }

    const float* Ac = &As[cur][0];
    const float* Bc = &Bs[cur][0];
    #pragma unroll
    for (int kk4 = 0; kk4 < 4; kk4++) {
      float4 a[8];
      #pragma unroll
      for (int i = 0; i < 8; i++)
        a[i] = *(const float4*)&Ac[(ty*8 + i)*16 + ((kk4 ^ ty) << 2)];
      #pragma unroll
      for (int s = 0; s < 4; s++) {
        const int kk = kk4*4 + s;
        float4 b0 = *(const float4*)&Bc[kk*64 + tx*4];
        #pragma unroll
        for (int i = 0; i < 8; i++) {
          const float as = (s==0) ? a[i].x : (s==1) ? a[i].y
                         : (s==2) ? a[i].z : a[i].w;
          acc[i][0] += as * b0.x;  acc[i][1] += as * b0.y;
          acc[i][2] += as * b0.z;  acc[i][3] += as * b0.w;
        }
      }
    }
  }

  const int head = n0 >> 6;
  const int d0 = tx * 4;
  #pragma unroll
  for (int i = 0; i < 8; i++) {
    int m = m0 + ty*8 + i;
    int b = m >> 11, l = m & 2047;
    float* drow = &dst[(((size_t)b*Hh + head)*Ll + l)*DKq];
    #pragma unroll
    for (int j = 0; j < 4; j++) drow[d0 + j] = acc[i][j] + bias[n0 + tx*4 + j];
  }
}

// ---------------------------------------------------------------------------
// LSH hash (unchanged)
// ---------------------------------------------------------------------------
__global__ __launch_bounds__(256) void hash_kernel(
    const float* __restrict__ qb, const float* __restrict__ kb,
    const float* __restrict__ rv, int* __restrict__ qhash, int* __restrict__ khash)
{
  int gwave = (blockIdx.x * blockDim.x + threadIdx.x) >> 6;
  int lane = threadIdx.x & 63;
  const int NR = Bb * Hh * Ll;
  if (gwave >= 2 * NR) return;
  int isK = gwave >= NR;
  int row = isK ? gwave - NR : gwave;
  int h = (row >> 11) & 7;
  const float* src = isK ? kb : qb;
  float x = src[(size_t)row * DKq + lane];
  float r = rv[h * DKq + lane];
  float v = (x > 0.0f) ? r : 0.0f;
  #pragma unroll
  for (int off = 32; off; off >>= 1) v += __shfl_xor(v, off);
  if (lane == 0) {
    float fb = floorf(v * 0.125f);
    int ib = (int)fb;
    int bucket = ib & 15;
    (isK ? khash : qhash)[row] = bucket;
  }
}

// ---------------------------------------------------------------------------
// First <=64 ascending key indices per (b,h,bucket) (unchanged)
// ---------------------------------------------------------------------------
__global__ __launch_bounds__(64) void kcand_kernel(
    const int* __restrict__ khash, int* __restrict__ kcand, int* __restrict__ kcount)
{
  int bh = blockIdx.x >> 4;
  int bucket = blockIdx.x & 15;
  int lane = threadIdx.x;
  const int* kh = &khash[bh * Ll];
  int* cl = &kcand[(size_t)blockIdx.x * KMAX];
  int total = 0;
  for (int c0 = 0; c0 < Ll && total < KMAX; c0 += 64) {
    int hv = kh[c0 + lane];
    unsigned long long m = __ballot(hv == bucket);
    int pre = __popcll(m & ((1ULL << lane) - 1ULL));
    if (hv == bucket && total + pre < KMAX) cl[total + pre] = c0 + lane;
    total += __popcll(m);
  }
  if (lane == 0) kcount[blockIdx.x] = total < KMAX ? total : KMAX;
}

// ---------------------------------------------------------------------------
// Group queries by bucket per (b,h) (unchanged)
// ---------------------------------------------------------------------------
__global__ __launch_bounds__(256) void qlist_kernel(
    const int* __restrict__ qhash, int* __restrict__ qoff, int* __restrict__ qlist)
{
  int bh = blockIdx.x;
  __shared__ int cnt[NBUCK], cur[NBUCK], off[NBUCK + 1];
  if (threadIdx.x < NBUCK) cnt[threadIdx.x] = 0;
  __syncthreads();
  const int* qh = &qhash[bh * Ll];
  for (int l = threadIdx.x; l < Ll; l += 256) atomicAdd(&cnt[qh[l]], 1);
  __syncthreads();
  if (threadIdx.x == 0) {
    int s = 0;
    for (int i = 0; i < NBUCK; i++) { off[i] = s; cur[i] = s; s += cnt[i]; }
    off[NBUCK] = s;
  }
  __syncthreads();
  if (threadIdx.x < NBUCK + 1) qoff[bh * (NBUCK + 1) + threadIdx.x] = off[threadIdx.x];
  for (int l = threadIdx.x; l < Ll; l += 256) {
    int p = atomicAdd(&cur[qh[l]], 1);
    qlist[bh * Ll + p] = l;
  }
}

// ---------------------------------------------------------------------------
// Deterministic worklist (unchanged)
// ---------------------------------------------------------------------------
__global__ __launch_bounds__(256) void worklist_kernel(
    const int* __restrict__ qoff, const int* __restrict__ kcount,
    int4* __restrict__ items, int* __restrict__ nitems)
{
  int t = threadIdx.x;
  int bh = t >> 4, bucket = t & 15;
  int o0 = qoff[bh * 17 + bucket], o1 = qoff[bh * 17 + bucket + 1];
  int cnt = kcount[t];
  int nq = o1 - o0;
  int n = (cnt > 0) ? ((nq + 31) >> 5) : 0;
  __shared__ int sc[256];
  sc[t] = n;
  __syncthreads();
  for (int off = 1; off < 256; off <<= 1) {
    int v = (t >= off) ? sc[t - off] : 0;
    __syncthreads();
    sc[t] += v;
    __syncthreads();
  }
  int start = sc[t] - n;
  for (int i = 0; i < n; i++) {
    int q0 = 32 * i;
    int qn = nq - q0; if (qn > 32) qn = 32;
    items[start + i] = make_int4(t, o0 + q0, qn, cnt);
  }
  if (t == 255) nitems[0] = sc[255];
}

// ---------------------------------------------------------------------------
// LDS fence for same-wave cross-lane LDS dependences (rule #18).
// ---------------------------------------------------------------------------
__device__ __forceinline__ void lds_fence() {
  asm volatile("s_waitcnt lgkmcnt(0)" ::: "memory");
  __builtin_amdgcn_sched_barrier(0);
}

// ---------------------------------------------------------------------------
// Attention: one WAVE per item (<=32 q x <=64 cand x 64 dim).  K rows in
// regs (lane=c), V^T in regs (lane=d), Q via wave-private LDS broadcasts.
// (unchanged -- correctness-verified rounds 4/6-13)
// ---------------------------------------------------------------------------
__global__ __launch_bounds__(256, 2) void attn_kernel(
    const float* __restrict__ qb, const float* __restrict__ kb, const float* __restrict__ vb,
    const int* __restrict__ qlist, const int* __restrict__ kcand,
    const int4* __restrict__ items, const int* __restrict__ nitems,
    float* __restrict__ ctx)
{
  __shared__ float qs_all[4][32 * 64];
  __shared__ float sa_all[4][64];
  const int wid = threadIdx.x >> 6, lane = threadIdx.x & 63;
  const int idx = blockIdx.x * 4 + wid;
  if (idx >= nitems[0]) return;          // wave-uniform exit
  const int4 it = items[idx];
  const int code = it.x, qstart = it.y, qn = it.z, cnt = it.w;
  const int bh = code >> 4;
  float* qs = qs_all[wid];
  float* sa = sa_all[wid];

  const float* qbh = qb + (size_t)bh * Ll * DKq;
  const float* kbh = kb + (size_t)bh * Ll * DKq;
  const float* vbh = vb + (size_t)bh * Ll * DKq;

  int qidx_v = (lane < qn)  ? qlist[bh * Ll + qstart + lane] : 0;
  int cidx_v = (lane < cnt) ? kcand[(size_t)code * KMAX + lane] : 0;

  float4 kr[16];
  {
    const float4* krow = (const float4*)kbh + (size_t)cidx_v * 16;
    #pragma unroll
    for (int i = 0; i < 16; i++) kr[i] = krow[i];
  }
  float vt[64];
  #pragma unroll
  for (int c = 0; c < 64; c++) {
    int rowc = __shfl(cidx_v, c);
    vt[c] = vbh[(size_t)rowc * DKq + lane];
  }
  #pragma unroll
  for (int i = 0; i < 8; i++) {
    int f = lane + 64 * i;
    int r = f >> 4, c4 = f & 15;
    int qrow = __shfl(qidx_v, r);
    float4 qv = *((const float4*)qbh + (size_t)qrow * 16 + c4);
    *(float4*)&qs[r * 64 + c4 * 4] = qv;
  }
  lds_fence();

  const int b = bh >> 3, h = bh & 7;
  const float4* qs4 = (const float4*)qs;
  const float4* sa4 = (const float4*)sa;

  for (int j = 0; j < qn; j++) {
    float s0 = 0.f, s1 = 0.f, s2 = 0.f, s3 = 0.f;
    #pragma unroll
    for (int i = 0; i < 16; i += 4) {
      float4 q0 = qs4[j * 16 + i + 0];
      float4 q1 = qs4[j * 16 + i + 1];
      float4 q2 = qs4[j * 16 + i + 2];
      float4 q3 = qs4[j * 16 + i + 3];
      s0 += q0.x*kr[i+0].x + q0.y*kr[i+0].y + q0.z*kr[i+0].z + q0.w*kr[i+0].w;
      s1 += q1.x*kr[i+1].x + q1.y*kr[i+1].y + q1.z*kr[i+1].z + q1.w*kr[i+1].w;
      s2 += q2.x*kr[i+2].x + q2.y*kr[i+2].y + q2.z*kr[i+2].z + q2.w*kr[i+2].w;
      s3 += q3.x*kr[i+3].x + q3.y*kr[i+3].y + q3.z*kr[i+3].z + q3.w*kr[i+3].w;
    }
    float s = ((s0 + s1) + (s2 + s3)) * 0.125f;
    s = (lane < cnt) ? s : -INFINITY;
    float m = s;
    #pragma unroll
    for (int off = 32; off; off >>= 1) m = fmaxf(m, __shfl_xor(m, off));
    float e = __expf(s - m);
    float sum = e;
    #pragma unroll
    for (int off = 32; off; off >>= 1) sum += __shfl_xor(sum, off);
    lds_fence();
    sa[lane] = e;
    lds_fence();
    float c0 = 0.f, c1 = 0.f, c2 = 0.f, c3 = 0.f;
    #pragma unroll
    for (int i = 0; i < 16; i++) {
      float4 a = sa4[i];
      c0 += a.x * vt[4*i + 0];
      c1 += a.y * vt[4*i + 1];
      c2 += a.z * vt[4*i + 2];
      c3 += a.w * vt[4*i + 3];
    }
    float ctxd = ((c0 + c1) + (c2 + c3)) / sum;
    int qrow = __shfl(qidx_v, j);
    ctx[((size_t)(b * Ll + qrow)) * 512 + h * 64 + lane] = ctxd;
  }
}

// ---------------------------------------------------------------------------
// T[h,dk,n] = sum_r U[h,dk,r] * V[h,r,n]  (unchanged)
// ---------------------------------------------------------------------------
__global__ __launch_bounds__(256) void uv_kernel(
    const float* __restrict__ U, const float* __restrict__ V, float* __restrict__ T)
{
  int idx = blockIdx.x * 256 + threadIdx.x;
  int n = idx & 511, dk = (idx >> 9) & 63, h = idx >> 15;
  float acc = 0.f;
  #pragma unroll
  for (int r = 0; r < 32; r++)
    acc += U[((size_t)h * 64 + dk) * 32 + r] * V[((size_t)h * 32 + r) * 512 + n];
  T[idx] = acc;
}

// ---------------------------------------------------------------------------
// Mf[h*64+dk, n] = sum_c T[h,dk,c] * Wo[h*512+c, n].
// Round-14(b): single-wave template (same as proj): BM=32 BN=64 BK=16,
// grid (8 n, 2 m, 8 h) = 128 blocks, counted vmcnt(6), no barrier.
// (Local pointers renamed Tb/Wb -- Bb is the batch macro.)
// ---------------------------------------------------------------------------
__global__ __launch_bounds__(64) void m_kernel(
    const float* __restrict__ T, const float* __restrict__ Wo, float* __restrict__ Mf)
{
  __shared__ float As[2][32 * 16];
  __shared__ float Bs[2][16 * 64];
  const int lane = threadIdx.x;
  const int h  = blockIdx.z;
  const int m0 = blockIdx.y * 32;          // row within this head's 64
  const int n0 = blockIdx.x * 64;
  const int tx = lane & 15, ty = lane >> 4;

  const float* Tb = T + (size_t)h * 64 * 512;      // 64 x 512
  const float* Wb = Wo + (size_t)h * 512 * 512;    // 512 x 512

  const float* aSrc[2];
  #pragma unroll
  for (int j = 0; j < 2; j++) {
    int row  = 16*j + (lane >> 2);
    int key  = (row >> 3) & 3;
    int sK4  = (lane & 3) ^ key;
    aSrc[j] = Tb + (size_t)(m0 + row) * 512 + (sK4 << 2);
  }
  const float* bSrc[4];
  #pragma unroll
  for (int j = 0; j < 4; j++) {
    int krow = 4*j + (lane >> 4);
    bSrc[j] = Wb + (size_t)krow * 512 + n0 + ((lane & 15) << 2);
  }

  #pragma unroll
  for (int j = 0; j < 2; j++) gl_lds16(aSrc[j], &As[0][j*256]);
  #pragma unroll
  for (int j = 0; j < 4; j++) gl_lds16(bSrc[j], &Bs[0][j*256]);

  float acc[8][4] = {};
  for (int t = 0; t < 32; t++) {
    const int cur = t & 1;
    if (t < 31) {
      const int ks = (t + 1) * 16;
      const int nb = cur ^ 1;
      #pragma unroll
      for (int j = 0; j < 2; j++) gl_lds16(aSrc[j] + ks,              &As[nb][j*256]);
      #pragma unroll
      for (int j = 0; j < 4; j++) gl_lds16(bSrc[j] + (size_t)ks*512,  &Bs[nb][j*256]);
      VM_WAIT(6);
    } else {
      VM_WAIT(0);
    }

    const float* Ac = &As[cur][0];
    const float* Bc = &Bs[cur][0];
    #pragma unroll
    for (int kk4 = 0; kk4 < 4; kk4++) {
      float4 a[8];
      #pragma unroll
      for (int i = 0; i < 8; i++)
        a[i] = *(const float4*)&Ac[(ty*8 + i)*16 + ((kk4 ^ ty) << 2)];
      #pragma unroll
      for (int s = 0; s < 4; s++) {
        const int kk = kk4*4 + s;
        float4 b0 = *(const float4*)&Bc[kk*64 + tx*4];
        #pragma unroll
        for (int i = 0; i < 8; i++) {
          const float as = (s==0) ? a[i].x : (s==1) ? a[i].y
                         : (s==2) ? a[i].z : a[i].w;
          acc[i][0] += as * b0.x;  acc[i][1] += as * b0.y;
          acc[i][2] += as * b0.z;  acc[i][3] += as * b0.w;
        }
      }
    }
  }

  #pragma unroll
  for (int i = 0; i < 8; i++) {
    int row = h*64 + m0 + ty*8 + i;
    #pragma unroll
    for (int j = 0; j < 4; j++)
      Mf[(size_t)row * 512 + n0 + tx*4 + j] = acc[i][j];
  }
}

// ---------------------------------------------------------------------------
// OUT(4096x512) = CTX @ Mf + bo.
// Round-14(b): single-wave template (same as proj): BM=32 BN=64 BK=16,
// grid (8,128) = 1024 blocks = 4 waves/CU, counted vmcnt(6), no barrier.
// ---------------------------------------------------------------------------
__global__ __launch_bounds__(64) void out_gemm(
    const float* __restrict__ A, const float* __restrict__ Bm,
    const float* __restrict__ bias, float* __restrict__ C)
{
  __shared__ float As[2][32 * 16];
  __shared__ float Bs[2][16 * 64];
  const int lane = threadIdx.x;
  const int m0 = blockIdx.y * 32;
  const int n0 = blockIdx.x * 64;
  const int tx = lane & 15, ty = lane >> 4;

  const float* aSrc[2];
  #pragma unroll
  for (int j = 0; j < 2; j++) {
    int row  = 16*j + (lane >> 2);
    int key  = (row >> 3) & 3;
    int sK4  = (lane & 3) ^ key;
    aSrc[j] = A + (size_t)(m0 + row) * 512 + (sK4 << 2);
  }
  const float* bSrc[4];
  #pragma unroll
  for (int j = 0; j < 4; j++) {
    int krow = 4*j + (lane >> 4);
    bSrc[j] = Bm + (size_t)krow * 512 + n0 + ((lane & 15) << 2);
  }

  #pragma unroll
  for (int j = 0; j < 2; j++) gl_lds16(aSrc[j], &As[0][j*256]);
  #pragma unroll
  for (int j = 0; j < 4; j++) gl_lds16(bSrc[j], &Bs[0][j*256]);

  float acc[8][4] = {};
  for (int t = 0; t < 32; t++) {
    const int cur = t & 1;
    if (t < 31) {
      const int ks = (t + 1) * 16;
      const int nb = cur ^ 1;
      #pragma unroll
      for (int j = 0; j < 2; j++) gl_lds16(aSrc[j] + ks,              &As[nb][j*256]);
      #pragma unroll
      for (int j = 0; j < 4; j++) gl_lds16(bSrc[j] + (size_t)ks*512,  &Bs[nb][j*256]);
      VM_WAIT(6);
    } else {
      VM_WAIT(0);
    }

    const float* Ac = &As[cur][0];
    const float* Bc = &Bs[cur][0];
    #pragma unroll
    for (int kk4 = 0; kk4 < 4; kk4++) {
      float4 a[8];
      #pragma unroll
      for (int i = 0; i < 8; i++)
        a[i] = *(const float4*)&Ac[(ty*8 + i)*16 + ((kk4 ^ ty) << 2)];
      #pragma unroll
      for (int s = 0; s < 4; s++) {
        const int kk = kk4*4 + s;
        float4 b0 = *(const float4*)&Bc[kk*64 + tx*4];
        #pragma unroll
        for (int i = 0; i < 8; i++) {
          const float as = (s==0) ? a[i].x : (s==1) ? a[i].y
                         : (s==2) ? a[i].z : a[i].w;
          acc[i][0] += as * b0.x;  acc[i][1] += as * b0.y;
          acc[i][2] += as * b0.z;  acc[i][3] += as * b0.w;
        }
      }
    }
  }

  #pragma unroll
  for (int i = 0; i < 8; i++) {
    int m = m0 + ty*8 + i;
    #pragma unroll
    for (int j = 0; j < 4; j++) {
      int n = n0 + tx*4 + j;
      C[(size_t)m * 512 + n] = acc[i][j] + bias[n];
    }
  }
}

// ---------------------------------------------------------------------------
extern "C" void kernel_launch(void* const* d_in, const int* in_sizes, int n_in,
                              void* d_out, int out_size, void* d_ws, size_t ws_size,
                              hipStream_t stream)
{
  const float* query = (const float*)d_in[0];
  const float* key   = (const float*)d_in[1];
  const float* value = (const float*)d_in[2];
  const float* Wq = (const float*)d_in[3];
  const float* bq = (const float*)d_in[4];
  const float* Wk = (const float*)d_in[5];
  const float* bk = (const float*)d_in[6];
  const float* Wv = (const float*)d_in[7];
  const float* bv = (const float*)d_in[8];
  const float* U  = (const float*)d_in[9];
  const float* V  = (const float*)d_in[10];
  const float* rv = (const float*)d_in[11];
  const float* Wo = (const float*)d_in[12];
  const float* bo = (const float*)d_in[13];
  float* out = (float*)d_out;

  float* ws = (float*)d_ws;
  const size_t NQKV = (size_t)Bb * Hh * Ll * DKq;
  float* qb   = ws;
  float* kb   = qb + NQKV;
  float* vb   = kb + NQKV;
  float* ctx  = vb + NQKV;
  float* T    = ctx + NQKV;
  float* Mf   = T + (size_t)Hh * DKq * 512;
  int* qhash  = (int*)(Mf + 512 * 512);
  int* khash  = qhash + Bb * Hh * Ll;
  int* kcand  = khash + Bb * Hh * Ll;
  int* kcount = kcand + Bb * Hh * NBUCK * KMAX;
  int* qoff   = kcount + Bb * Hh * NBUCK;
  int* qlist  = qoff + Bb * Hh * (NBUCK + 1);
  int4* items = (int4*)(qlist + Bb * Hh * Ll);    // 16B-aligned offset
  int* nitems = (int*)(items + MAX_ITEMS);

  proj_kernel<<<dim3(8, 128, 3), 64, 0, stream>>>(query, key, value,
                                                  Wq, Wk, Wv, bq, bk, bv,
                                                  qb, kb, vb);
  hash_kernel<<<(2 * Bb * Hh * Ll * 64) / 256, 256, 0, stream>>>(qb, kb, rv, qhash, khash);
  kcand_kernel<<<Bb * Hh * NBUCK, 64, 0, stream>>>(khash, kcand, kcount);
  qlist_kernel<<<Bb * Hh, 256, 0, stream>>>(qhash, qoff, qlist);
  worklist_kernel<<<1, 256, 0, stream>>>(qoff, kcount, items, nitems);
  attn_kernel<<<MAX_ITEMS / 4, 256, 0, stream>>>(qb, kb, vb, qlist, kcand,
                                                 items, nitems, ctx);
  uv_kernel<<<(Hh * DKq * 512) / 256, 256, 0, stream>>>(U, V, T);
  m_kernel<<<dim3(8, 2, 8), 64, 0, stream>>>(T, Wo, Mf);
  out_gemm<<<dim3(8, 128), 64, 0, stream>>>(ctx, Mf, bo, out);
}

// Round 16
// 252.612 us; speedup vs baseline: 1.0542x; 1.0268x over previous
//
#include <hip/hip_runtime.h>
#include <math.h>

// Problem constants (from reference)
#define Bb 2
#define Ll 2048
#define Dd 512
#define Hh 8
#define DKq 64
#define NBUCK 16
#define KMAX 64
#define MAX_ITEMS 2304   // chunk-16 bound: 16 bh * (128 + 16) = 2304

// ---------------------------------------------------------------------------
// Direct global->LDS DMA (gfx950), 16B per lane.  LDS dest = uniform base +
// lane*16 (linear); per-lane GLOBAL address carries any swizzle (m173/m201).
// ---------------------------------------------------------------------------
__device__ __forceinline__ void gl_lds16(const float* g, float* l) {
  __builtin_amdgcn_global_load_lds(
      (const __attribute__((address_space(1))) void*)g,
      (__attribute__((address_space(3))) void*)l, 16, 0, 0);
}

// Counted vmcnt wait, NO barrier (single-wave blocks are self-paced).
// vmcnt retires IN ORDER (round-11 lesson): with only staging DMAs on the
// counter, vmcnt(6) == "tile t's 6 loads done, t+1's 6 may fly".
#define VM_WAIT(N)                                                \
  do {                                                            \
    asm volatile("s_waitcnt vmcnt(" #N ")" ::: "memory");         \
    __builtin_amdgcn_sched_barrier(0);                            \
  } while (0)

// ---------------------------------------------------------------------------
// Projection GEMM (UNCHANGED from round 13 -- ~94 us, VALUBusy ~58%).
// Single-wave blocks, BM=32 BN=64 BK=16, 8x4 microtile, grid (8,128,3) =
// 3072 blocks = 12 waves/CU.  DMA staging + counted vmcnt(6), no barrier.
// Per-output FMA chain is ascending-k -> bit-identical q/k (LSH-critical).
// ---------------------------------------------------------------------------
__global__ __launch_bounds__(64) void proj_kernel(
    const float* __restrict__ Xq, const float* __restrict__ Xk, const float* __restrict__ Xv,
    const float* __restrict__ Wq, const float* __restrict__ Wk, const float* __restrict__ Wv,
    const float* __restrict__ bq, const float* __restrict__ bk, const float* __restrict__ bv,
    float* __restrict__ qb, float* __restrict__ kb, float* __restrict__ vb)
{
  const float *X, *W, *bias; float* dst;
  if (blockIdx.z == 0)      { X=Xq; W=Wq; bias=bq; dst=qb; }
  else if (blockIdx.z == 1) { X=Xk; W=Wk; bias=bk; dst=kb; }
  else                      { X=Xv; W=Wv; bias=bv; dst=vb; }
  __shared__ float As[2][32 * 16];
  __shared__ float Bs[2][16 * 64];
  const int lane = threadIdx.x;
  const int m0 = blockIdx.y * 32;
  const int n0 = blockIdx.x * 64;
  const int tx = lane & 15, ty = lane >> 4;

  const float* aSrc[2];
  #pragma unroll
  for (int j = 0; j < 2; j++) {
    int row  = 16*j + (lane >> 2);
    int key  = (row >> 3) & 3;
    int sK4  = (lane & 3) ^ key;
    aSrc[j] = X + (size_t)(m0 + row) * 512 + (sK4 << 2);
  }
  const float* bSrc[4];
  #pragma unroll
  for (int j = 0; j < 4; j++) {
    int krow = 4*j + (lane >> 4);
    bSrc[j] = W + (size_t)krow * 512 + n0 + ((lane & 15) << 2);
  }

  #pragma unroll
  for (int j = 0; j < 2; j++) gl_lds16(aSrc[j], &As[0][j*256]);
  #pragma unroll
  for (int j = 0; j < 4; j++) gl_lds16(bSrc[j], &Bs[0][j*256]);

  float acc[8][4] = {};
  for (int t = 0; t < 32; t++) {
    const int cur = t & 1;
    if (t < 31) {
      const int ks = (t + 1) * 16;
      const int nb = cur ^ 1;
      #pragma unroll
      for (int j = 0; j < 2; j++) gl_lds16(aSrc[j] + ks,              &As[nb][j*256]);
      #pragma unroll
      for (int j = 0; j < 4; j++) gl_lds16(bSrc[j] + (size_t)ks*512,  &Bs[nb][j*256]);
      VM_WAIT(6);
    } else {
      VM_WAIT(0);
    }

    const float* Ac = &As[cur][0];
    const float* Bc = &Bs[cur][0];
    #pragma unroll
    for (int kk4 = 0; kk4 < 4; kk4++) {
      float4 a[8];
      #pragma unroll
      for (int i = 0; i < 8; i++)
        a[i] = *(const float4*)&Ac[(ty*8 + i)*16 + ((kk4 ^ ty) << 2)];
      #pragma unroll
      for (int s = 0; s < 4; s++) {
        const int kk = kk4*4 + s;
        float4 b0 = *(const float4*)&Bc[kk*64 + tx*4];
        #pragma unroll
        for (int i = 0; i < 8; i++) {
          const float as = (s==0) ? a[i].x : (s==1) ? a[i].y
                         : (s==2) ? a[i].z : a[i].w;
          acc[i][0] += as * b0.x;  acc[i][1] += as * b0.y;
          acc[i][2] += as * b0.z;  acc[i][3] += as * b0.w;
        }
      }
    }
  }

  const int head = n0 >> 6;
  const int d0 = tx * 4;
  #pragma unroll
  for (int i = 0; i < 8; i++) {
    int m = m0 + ty*8 + i;
    int b = m >> 11, l = m & 2047;
    float* drow = &dst[(((size_t)b*Hh + head)*Ll + l)*DKq];
    #pragma unroll
    for (int j = 0; j < 4; j++) drow[d0 + j] = acc[i][j] + bias[n0 + tx*4 + j];
  }
}

// ---------------------------------------------------------------------------
// LSH hash (unchanged)
// ---------------------------------------------------------------------------
__global__ __launch_bounds__(256) void hash_kernel(
    const float* __restrict__ qb, const float* __restrict__ kb,
    const float* __restrict__ rv, int* __restrict__ qhash, int* __restrict__ khash)
{
  int gwave = (blockIdx.x * blockDim.x + threadIdx.x) >> 6;
  int lane = threadIdx.x & 63;
  const int NR = Bb * Hh * Ll;
  if (gwave >= 2 * NR) return;
  int isK = gwave >= NR;
  int row = isK ? gwave - NR : gwave;
  int h = (row >> 11) & 7;
  const float* src = isK ? kb : qb;
  float x = src[(size_t)row * DKq + lane];
  float r = rv[h * DKq + lane];
  float v = (x > 0.0f) ? r : 0.0f;
  #pragma unroll
  for (int off = 32; off; off >>= 1) v += __shfl_xor(v, off);
  if (lane == 0) {
    float fb = floorf(v * 0.125f);
    int ib = (int)fb;
    int bucket = ib & 15;
    (isK ? khash : qhash)[row] = bucket;
  }
}

// ---------------------------------------------------------------------------
// First <=64 ascending key indices per (b,h,bucket) (unchanged)
// ---------------------------------------------------------------------------
__global__ __launch_bounds__(64) void kcand_kernel(
    const int* __restrict__ khash, int* __restrict__ kcand, int* __restrict__ kcount)
{
  int bh = blockIdx.x >> 4;
  int bucket = blockIdx.x & 15;
  int lane = threadIdx.x;
  const int* kh = &khash[bh * Ll];
  int* cl = &kcand[(size_t)blockIdx.x * KMAX];
  int total = 0;
  for (int c0 = 0; c0 < Ll && total < KMAX; c0 += 64) {
    int hv = kh[c0 + lane];
    unsigned long long m = __ballot(hv == bucket);
    int pre = __popcll(m & ((1ULL << lane) - 1ULL));
    if (hv == bucket && total + pre < KMAX) cl[total + pre] = c0 + lane;
    total += __popcll(m);
  }
  if (lane == 0) kcount[blockIdx.x] = total < KMAX ? total : KMAX;
}

// ---------------------------------------------------------------------------
// Group queries by bucket per (b,h) (unchanged)
// ---------------------------------------------------------------------------
__global__ __launch_bounds__(256) void qlist_kernel(
    const int* __restrict__ qhash, int* __restrict__ qoff, int* __restrict__ qlist)
{
  int bh = blockIdx.x;
  __shared__ int cnt[NBUCK], cur[NBUCK], off[NBUCK + 1];
  if (threadIdx.x < NBUCK) cnt[threadIdx.x] = 0;
  __syncthreads();
  const int* qh = &qhash[bh * Ll];
  for (int l = threadIdx.x; l < Ll; l += 256) atomicAdd(&cnt[qh[l]], 1);
  __syncthreads();
  if (threadIdx.x == 0) {
    int s = 0;
    for (int i = 0; i < NBUCK; i++) { off[i] = s; cur[i] = s; s += cnt[i]; }
    off[NBUCK] = s;
  }
  __syncthreads();
  if (threadIdx.x < NBUCK + 1) qoff[bh * (NBUCK + 1) + threadIdx.x] = off[threadIdx.x];
  for (int l = threadIdx.x; l < Ll; l += 256) {
    int p = atomicAdd(&cur[qh[l]], 1);
    qlist[bh * Ll + p] = l;
  }
}

// ---------------------------------------------------------------------------
// Deterministic worklist: one item per active (bh,bucket,chunk-of-16-queries).
// Chunk 16 (was 32): ~2x items -> ~8 waves/CU in attn (TLP was the limit).
// ---------------------------------------------------------------------------
__global__ __launch_bounds__(256) void worklist_kernel(
    const int* __restrict__ qoff, const int* __restrict__ kcount,
    int4* __restrict__ items, int* __restrict__ nitems)
{
  int t = threadIdx.x;
  int bh = t >> 4, bucket = t & 15;
  int o0 = qoff[bh * 17 + bucket], o1 = qoff[bh * 17 + bucket + 1];
  int cnt = kcount[t];
  int nq = o1 - o0;
  int n = (cnt > 0) ? ((nq + 15) >> 4) : 0;
  __shared__ int sc[256];
  sc[t] = n;
  __syncthreads();
  for (int off = 1; off < 256; off <<= 1) {
    int v = (t >= off) ? sc[t - off] : 0;
    __syncthreads();
    sc[t] += v;
    __syncthreads();
  }
  int start = sc[t] - n;
  for (int i = 0; i < n; i++) {
    int q0 = 16 * i;
    int qn = nq - q0; if (qn > 16) qn = 16;
    items[start + i] = make_int4(t, o0 + q0, qn, cnt);
  }
  if (t == 255) nitems[0] = sc[255];
}

// ---------------------------------------------------------------------------
// LDS fence for same-wave cross-lane LDS dependences (rule #18).
// ---------------------------------------------------------------------------
__device__ __forceinline__ void lds_fence() {
  asm volatile("s_waitcnt lgkmcnt(0)" ::: "memory");
  __builtin_amdgcn_sched_barrier(0);
}

// ---------------------------------------------------------------------------
// Attention v4: one WAVE per item (<=16 q x <=64 cand x 64 dim).  K rows in
// regs (lane=c), V^T in regs (lane=d), Q via wave-private LDS broadcasts.
// Round-16: chunk 16 (2x waves = 8/CU) + PAIRED query processing -- two
// QK dots / dual shfl reduces / one sa[128] write + one fence pair / dual
// PV chains per 2 queries.  Halves the serial fence count and doubles ILP.
// Invalid trailing query: clamped row (j1r=j0), store guarded.
// ---------------------------------------------------------------------------
__global__ __launch_bounds__(256, 2) void attn_kernel(
    const float* __restrict__ qb, const float* __restrict__ kb, const float* __restrict__ vb,
    const int* __restrict__ qlist, const int* __restrict__ kcand,
    const int4* __restrict__ items, const int* __restrict__ nitems,
    float* __restrict__ ctx)
{
  __shared__ float qs_all[4][16 * 64];
  __shared__ float sa_all[4][128];
  const int wid = threadIdx.x >> 6, lane = threadIdx.x & 63;
  const int idx = blockIdx.x * 4 + wid;
  if (idx >= nitems[0]) return;          // wave-uniform exit
  const int4 it = items[idx];
  const int code = it.x, qstart = it.y, qn = it.z, cnt = it.w;
  const int bh = code >> 4;
  float* qs = qs_all[wid];
  float* sa = sa_all[wid];

  const float* qbh = qb + (size_t)bh * Ll * DKq;
  const float* kbh = kb + (size_t)bh * Ll * DKq;
  const float* vbh = vb + (size_t)bh * Ll * DKq;

  int qidx_v = (lane < qn)  ? qlist[bh * Ll + qstart + lane] : 0;
  int cidx_v = (lane < cnt) ? kcand[(size_t)code * KMAX + lane] : 0;

  float4 kr[16];
  {
    const float4* krow = (const float4*)kbh + (size_t)cidx_v * 16;
    #pragma unroll
    for (int i = 0; i < 16; i++) kr[i] = krow[i];
  }
  float vt[64];
  #pragma unroll
  for (int c = 0; c < 64; c++) {
    int rowc = __shfl(cidx_v, c);
    vt[c] = vbh[(size_t)rowc * DKq + lane];
  }
  // Stage Q chunk (16 rows x 64) into wave-private LDS.
  #pragma unroll
  for (int i = 0; i < 4; i++) {
    int f = lane + 64 * i;               // 0..255 float4 slots
    int r = f >> 4, c4 = f & 15;
    int qrow = __shfl(qidx_v, r);
    float4 qv = *((const float4*)qbh + (size_t)qrow * 16 + c4);
    *(float4*)&qs[r * 64 + c4 * 4] = qv;
  }
  lds_fence();

  const int b = bh >> 3, h = bh & 7;
  const float4* qs4 = (const float4*)qs;
  const float4* sa4 = (const float4*)sa;

  for (int jj = 0; jj < qn; jj += 2) {
    const int j0  = jj;
    const int j1v = jj + 1;                        // may be == qn (invalid)
    const int j1r = (j1v < qn) ? j1v : j0;         // clamped row (safe read)
    // ---- dual QK^T ----
    float p00=0.f,p01=0.f,p02=0.f,p03=0.f;
    float p10=0.f,p11=0.f,p12=0.f,p13=0.f;
    #pragma unroll
    for (int i = 0; i < 16; i += 4) {
      float4 qA0 = qs4[j0*16 + i + 0];
      float4 qA1 = qs4[j0*16 + i + 1];
      float4 qA2 = qs4[j0*16 + i + 2];
      float4 qA3 = qs4[j0*16 + i + 3];
      float4 qB0 = qs4[j1r*16 + i + 0];
      float4 qB1 = qs4[j1r*16 + i + 1];
      float4 qB2 = qs4[j1r*16 + i + 2];
      float4 qB3 = qs4[j1r*16 + i + 3];
      p00 += qA0.x*kr[i+0].x + qA0.y*kr[i+0].y + qA0.z*kr[i+0].z + qA0.w*kr[i+0].w;
      p01 += qA1.x*kr[i+1].x + qA1.y*kr[i+1].y + qA1.z*kr[i+1].z + qA1.w*kr[i+1].w;
      p02 += qA2.x*kr[i+2].x + qA2.y*kr[i+2].y + qA2.z*kr[i+2].z + qA2.w*kr[i+2].w;
      p03 += qA3.x*kr[i+3].x + qA3.y*kr[i+3].y + qA3.z*kr[i+3].z + qA3.w*kr[i+3].w;
      p10 += qB0.x*kr[i+0].x + qB0.y*kr[i+0].y + qB0.z*kr[i+0].z + qB0.w*kr[i+0].w;
      p11 += qB1.x*kr[i+1].x + qB1.y*kr[i+1].y + qB1.z*kr[i+1].z + qB1.w*kr[i+1].w;
      p12 += qB2.x*kr[i+2].x + qB2.y*kr[i+2].y + qB2.z*kr[i+2].z + qB2.w*kr[i+2].w;
      p13 += qB3.x*kr[i+3].x + qB3.y*kr[i+3].y + qB3.z*kr[i+3].z + qB3.w*kr[i+3].w;
    }
    float sA = ((p00 + p01) + (p02 + p03)) * 0.125f;
    float sB = ((p10 + p11) + (p12 + p13)) * 0.125f;
    sA = (lane < cnt) ? sA : -INFINITY;
    sB = (lane < cnt) ? sB : -INFINITY;
    // ---- dual softmax reduce (independent chains interleave) ----
    float mA = sA, mB = sB;
    #pragma unroll
    for (int off = 32; off; off >>= 1) {
      mA = fmaxf(mA, __shfl_xor(mA, off));
      mB = fmaxf(mB, __shfl_xor(mB, off));
    }
    float eA = __expf(sA - mA);
    float eB = __expf(sB - mB);
    float sumA = eA, sumB = eB;
    #pragma unroll
    for (int off = 32; off; off >>= 1) {
      sumA += __shfl_xor(sumA, off);
      sumB += __shfl_xor(sumB, off);
    }
    // ---- one fence pair per 2 queries ----
    lds_fence();                          // prior pair's sa reads complete
    sa[lane]      = eA;
    sa[64 + lane] = eB;
    lds_fence();                          // writes visible
    // ---- dual PV ----
    float c00=0.f,c01=0.f,c02=0.f,c03=0.f;
    float c10=0.f,c11=0.f,c12=0.f,c13=0.f;
    #pragma unroll
    for (int i = 0; i < 16; i++) {
      float4 aA = sa4[i];
      float4 aB = sa4[16 + i];
      c00 += aA.x * vt[4*i + 0];
      c01 += aA.y * vt[4*i + 1];
      c02 += aA.z * vt[4*i + 2];
      c03 += aA.w * vt[4*i + 3];
      c10 += aB.x * vt[4*i + 0];
      c11 += aB.y * vt[4*i + 1];
      c12 += aB.z * vt[4*i + 2];
      c13 += aB.w * vt[4*i + 3];
    }
    {
      float ctxd = ((c00 + c01) + (c02 + c03)) / sumA;
      int qrow = __shfl(qidx_v, j0);
      ctx[((size_t)(b * Ll + qrow)) * 512 + h * 64 + lane] = ctxd;
    }
    if (j1v < qn) {
      float ctxd = ((c10 + c11) + (c12 + c13)) / sumB;
      int qrow = __shfl(qidx_v, j1v);
      ctx[((size_t)(b * Ll + qrow)) * 512 + h * 64 + lane] = ctxd;
    }
  }
}

// ---------------------------------------------------------------------------
// T[h,dk,n] = sum_r U[h,dk,r] * V[h,r,n]  (unchanged)
// ---------------------------------------------------------------------------
__global__ __launch_bounds__(256) void uv_kernel(
    const float* __restrict__ U, const float* __restrict__ V, float* __restrict__ T)
{
  int idx = blockIdx.x * 256 + threadIdx.x;
  int n = idx & 511, dk = (idx >> 9) & 63, h = idx >> 15;
  float acc = 0.f;
  #pragma unroll
  for (int r = 0; r < 32; r++)
    acc += U[((size_t)h * 64 + dk) * 32 + r] * V[((size_t)h * 32 + r) * 512 + n];
  T[idx] = acc;
}

// ---------------------------------------------------------------------------
// Mf[h*64+dk, n] = sum_c T[h,dk,c] * Wo[h*512+c, n].  (unchanged R15)
// ---------------------------------------------------------------------------
__global__ __launch_bounds__(64) void m_kernel(
    const float* __restrict__ T, const float* __restrict__ Wo, float* __restrict__ Mf)
{
  __shared__ float As[2][32 * 16];
  __shared__ float Bs[2][16 * 64];
  const int lane = threadIdx.x;
  const int h  = blockIdx.z;
  const int m0 = blockIdx.y * 32;
  const int n0 = blockIdx.x * 64;
  const int tx = lane & 15, ty = lane >> 4;

  const float* Tb = T + (size_t)h * 64 * 512;
  const float* Wb = Wo + (size_t)h * 512 * 512;

  const float* aSrc[2];
  #pragma unroll
  for (int j = 0; j < 2; j++) {
    int row  = 16*j + (lane >> 2);
    int key  = (row >> 3) & 3;
    int sK4  = (lane & 3) ^ key;
    aSrc[j] = Tb + (size_t)(m0 + row) * 512 + (sK4 << 2);
  }
  const float* bSrc[4];
  #pragma unroll
  for (int j = 0; j < 4; j++) {
    int krow = 4*j + (lane >> 4);
    bSrc[j] = Wb + (size_t)krow * 512 + n0 + ((lane & 15) << 2);
  }

  #pragma unroll
  for (int j = 0; j < 2; j++) gl_lds16(aSrc[j], &As[0][j*256]);
  #pragma unroll
  for (int j = 0; j < 4; j++) gl_lds16(bSrc[j], &Bs[0][j*256]);

  float acc[8][4] = {};
  for (int t = 0; t < 32; t++) {
    const int cur = t & 1;
    if (t < 31) {
      const int ks = (t + 1) * 16;
      const int nb = cur ^ 1;
      #pragma unroll
      for (int j = 0; j < 2; j++) gl_lds16(aSrc[j] + ks,              &As[nb][j*256]);
      #pragma unroll
      for (int j = 0; j < 4; j++) gl_lds16(bSrc[j] + (size_t)ks*512,  &Bs[nb][j*256]);
      VM_WAIT(6);
    } else {
      VM_WAIT(0);
    }

    const float* Ac = &As[cur][0];
    const float* Bc = &Bs[cur][0];
    #pragma unroll
    for (int kk4 = 0; kk4 < 4; kk4++) {
      float4 a[8];
      #pragma unroll
      for (int i = 0; i < 8; i++)
        a[i] = *(const float4*)&Ac[(ty*8 + i)*16 + ((kk4 ^ ty) << 2)];
      #pragma unroll
      for (int s = 0; s < 4; s++) {
        const int kk = kk4*4 + s;
        float4 b0 = *(const float4*)&Bc[kk*64 + tx*4];
        #pragma unroll
        for (int i = 0; i < 8; i++) {
          const float as = (s==0) ? a[i].x : (s==1) ? a[i].y
                         : (s==2) ? a[i].z : a[i].w;
          acc[i][0] += as * b0.x;  acc[i][1] += as * b0.y;
          acc[i][2] += as * b0.z;  acc[i][3] += as * b0.w;
        }
      }
    }
  }

  #pragma unroll
  for (int i = 0; i < 8; i++) {
    int row = h*64 + m0 + ty*8 + i;
    #pragma unroll
    for (int j = 0; j < 4; j++)
      Mf[(size_t)row * 512 + n0 + tx*4 + j] = acc[i][j];
  }
}

// ---------------------------------------------------------------------------
// OUT(4096x512) = CTX @ Mf + bo.  (unchanged R15)
// ---------------------------------------------------------------------------
__global__ __launch_bounds__(64) void out_gemm(
    const float* __restrict__ A, const float* __restrict__ Bm,
    const float* __restrict__ bias, float* __restrict__ C)
{
  __shared__ float As[2][32 * 16];
  __shared__ float Bs[2][16 * 64];
  const int lane = threadIdx.x;
  const int m0 = blockIdx.y * 32;
  const int n0 = blockIdx.x * 64;
  const int tx = lane & 15, ty = lane >> 4;

  const float* aSrc[2];
  #pragma unroll
  for (int j = 0; j < 2; j++) {
    int row  = 16*j + (lane >> 2);
    int key  = (row >> 3) & 3;
    int sK4  = (lane & 3) ^ key;
    aSrc[j] = A + (size_t)(m0 + row) * 512 + (sK4 << 2);
  }
  const float* bSrc[4];
  #pragma unroll
  for (int j = 0; j < 4; j++) {
    int krow = 4*j + (lane >> 4);
    bSrc[j] = Bm + (size_t)krow * 512 + n0 + ((lane & 15) << 2);
  }

  #pragma unroll
  for (int j = 0; j < 2; j++) gl_lds16(aSrc[j], &As[0][j*256]);
  #pragma unroll
  for (int j = 0; j < 4; j++) gl_lds16(bSrc[j], &Bs[0][j*256]);

  float acc[8][4] = {};
  for (int t = 0; t < 32; t++) {
    const int cur = t & 1;
    if (t < 31) {
      const int ks = (t + 1) * 16;
      const int nb = cur ^ 1;
      #pragma unroll
      for (int j = 0; j < 2; j++) gl_lds16(aSrc[j] + ks,              &As[nb][j*256]);
      #pragma unroll
      for (int j = 0; j < 4; j++) gl_lds16(bSrc[j] + (size_t)ks*512,  &Bs[nb][j*256]);
      VM_WAIT(6);
    } else {
      VM_WAIT(0);
    }

    const float* Ac = &As[cur][0];
    const float* Bc = &Bs[cur][0];
    #pragma unroll
    for (int kk4 = 0; kk4 < 4; kk4++) {
      float4 a[8];
      #pragma unroll
      for (int i = 0; i < 8; i++)
        a[i] = *(const float4*)&Ac[(ty*8 + i)*16 + ((kk4 ^ ty) << 2)];
      #pragma unroll
      for (int s = 0; s < 4; s++) {
        const int kk = kk4*4 + s;
        float4 b0 = *(const float4*)&Bc[kk*64 + tx*4];
        #pragma unroll
        for (int i = 0; i < 8; i++) {
          const float as = (s==0) ? a[i].x : (s==1) ? a[i].y
                         : (s==2) ? a[i].z : a[i].w;
          acc[i][0] += as * b0.x;  acc[i][1] += as * b0.y;
          acc[i][2] += as * b0.z;  acc[i][3] += as * b0.w;
        }
      }
    }
  }

  #pragma unroll
  for (int i = 0; i < 8; i++) {
    int m = m0 + ty*8 + i;
    #pragma unroll
    for (int j = 0; j < 4; j++) {
      int n = n0 + tx*4 + j;
      C[(size_t)m * 512 + n] = acc[i][j] + bias[n];
    }
  }
}

// ---------------------------------------------------------------------------
extern "C" void kernel_launch(void* const* d_in, const int* in_sizes, int n_in,
                              void* d_out, int out_size, void* d_ws, size_t ws_size,
                              hipStream_t stream)
{
  const float* query = (const float*)d_in[0];
  const float* key   = (const float*)d_in[1];
  const float* value = (const float*)d_in[2];
  const float* Wq = (const float*)d_in[3];
  const float* bq = (const float*)d_in[4];
  const float* Wk = (const float*)d_in[5];
  const float* bk = (const float*)d_in[6];
  const float* Wv = (const float*)d_in[7];
  const float* bv = (const float*)d_in[8];
  const float* U  = (const float*)d_in[9];
  const float* V  = (const float*)d_in[10];
  const float* rv = (const float*)d_in[11];
  const float* Wo = (const float*)d_in[12];
  const float* bo = (const float*)d_in[13];
  float* out = (float*)d_out;

  float* ws = (float*)d_ws;
  const size_t NQKV = (size_t)Bb * Hh * Ll * DKq;
  float* qb   = ws;
  float* kb   = qb + NQKV;
  float* vb   = kb + NQKV;
  float* ctx  = vb + NQKV;
  float* T    = ctx + NQKV;
  float* Mf   = T + (size_t)Hh * DKq * 512;
  int* qhash  = (int*)(Mf + 512 * 512);
  int* khash  = qhash + Bb * Hh * Ll;
  int* kcand  = khash + Bb * Hh * Ll;
  int* kcount = kcand + Bb * Hh * NBUCK * KMAX;
  int* qoff   = kcount + Bb * Hh * NBUCK;
  int* qlist  = qoff + Bb * Hh * (NBUCK + 1);
  int4* items = (int4*)(qlist + Bb * Hh * Ll);    // 16B-aligned offset
  int* nitems = (int*)(items + MAX_ITEMS);

  proj_kernel<<<dim3(8, 128, 3), 64, 0, stream>>>(query, key, value,
                                                  Wq, Wk, Wv, bq, bk, bv,
                                                  qb, kb, vb);
  hash_kernel<<<(2 * Bb * Hh * Ll * 64) / 256, 256, 0, stream>>>(qb, kb, rv, qhash, khash);
  kcand_kernel<<<Bb * Hh * NBUCK, 64, 0, stream>>>(khash, kcand, kcount);
  qlist_kernel<<<Bb * Hh, 256, 0, stream>>>(qhash, qoff, qlist);
  worklist_kernel<<<1, 256, 0, stream>>>(qoff, kcount, items, nitems);
  attn_kernel<<<MAX_ITEMS / 4, 256, 0, stream>>>(qb, kb, vb, qlist, kcand,
                                                 items, nitems, ctx);
  uv_kernel<<<(Hh * DKq * 512) / 256, 256, 0, stream>>>(U, V, T);
  m_kernel<<<dim3(8, 2, 8), 64, 0, stream>>>(T, Wo, Mf);
  out_gemm<<<dim3(8, 128), 64, 0, stream>>>(ctx, Mf, bo, out);
}